// Round 1
// baseline (248.664 us; speedup 1.0000x reference)
//
#include <hip/hip_runtime.h>

// Problem constants (fixed by setup_inputs):
//   img:  [B=4, C=1, D=64, H=192, W=192]  fp32
//   flow: [B=4, 3,   D=64, H=192, W=192]  fp32
//   out:  [B=4, C=1, D=64, H=192, W=192]  fp32
#define B_  4
#define D_  64
#define H_  192
#define W_  192
#define HW_ (H_ * W_)
#define DHW_ (D_ * H_ * W_)
#define NTOT (B_ * DHW_)

__global__ __launch_bounds__(256) void warp3d_kernel(
    const float* __restrict__ img,
    const float* __restrict__ flow,
    float* __restrict__ out)
{
    int n = blockIdx.x * blockDim.x + threadIdx.x;
    if (n >= NTOT) return;

    int b = n / DHW_;
    int r = n - b * DHW_;          // spatial index within volume
    int z = r / HW_;
    int r2 = r - z * HW_;
    int y = r2 / W_;
    int x = r2 - y * W_;

    const float* fl = flow + (size_t)b * 3 * DHW_ + r;
    float fx = fl[0];
    float fy = fl[DHW_];
    float fz = fl[2 * DHW_];

    // ix = (x + fx) * W/(W-1) - 0.5, clipped to [0, W-1]; same for y,z.
    const float sx = (float)W_ / (float)(W_ - 1);
    const float sy = (float)H_ / (float)(H_ - 1);
    const float sz = (float)D_ / (float)(D_ - 1);

    float ix = ((float)x + fx) * sx - 0.5f;
    float iy = ((float)y + fy) * sy - 0.5f;
    float iz = ((float)z + fz) * sz - 0.5f;
    ix = fminf(fmaxf(ix, 0.0f), (float)(W_ - 1));
    iy = fminf(fmaxf(iy, 0.0f), (float)(H_ - 1));
    iz = fminf(fmaxf(iz, 0.0f), (float)(D_ - 1));

    float x0f = floorf(ix), y0f = floorf(iy), z0f = floorf(iz);
    float wx = ix - x0f, wy = iy - y0f, wz = iz - z0f;

    int x0 = (int)x0f;
    int y0 = (int)y0f;
    int z0 = (int)z0f;
    int x1 = min(x0 + 1, W_ - 1);
    int y1 = min(y0 + 1, H_ - 1);
    int z1 = min(z0 + 1, D_ - 1);

    const float* im = img + (size_t)b * DHW_;

    int bz0 = z0 * HW_;
    int bz1 = z1 * HW_;
    int r00 = bz0 + y0 * W_;
    int r01 = bz0 + y1 * W_;
    int r10 = bz1 + y0 * W_;
    int r11 = bz1 + y1 * W_;

    float v000 = im[r00 + x0], v001 = im[r00 + x1];
    float v010 = im[r01 + x0], v011 = im[r01 + x1];
    float v100 = im[r10 + x0], v101 = im[r10 + x1];
    float v110 = im[r11 + x0], v111 = im[r11 + x1];

    // trilinear lerp
    float c00 = v000 + wx * (v001 - v000);
    float c01 = v010 + wx * (v011 - v010);
    float c10 = v100 + wx * (v101 - v100);
    float c11 = v110 + wx * (v111 - v110);
    float c0 = c00 + wy * (c01 - c00);
    float c1 = c10 + wy * (c11 - c10);
    out[n] = c0 + wz * (c1 - c0);
}

extern "C" void kernel_launch(void* const* d_in, const int* in_sizes, int n_in,
                              void* d_out, int out_size, void* d_ws, size_t ws_size,
                              hipStream_t stream) {
    const float* img  = (const float*)d_in[0];
    const float* flow = (const float*)d_in[1];
    float* out = (float*)d_out;

    const int threads = 256;
    const int blocks = (NTOT + threads - 1) / threads;
    warp3d_kernel<<<blocks, threads, 0, stream>>>(img, flow, out);
}